// Round 9
// baseline (266.921 us; speedup 1.0000x reference)
//
#include <hip/hip_runtime.h>
#include <stdint.h>

#define Ttok 1024
#define Hdim 2048
#define Idim 1024
#define Enum 16

typedef __attribute__((ext_vector_type(8))) short  short8;
typedef __attribute__((ext_vector_type(4))) float  f32x4;

// barrier WITHOUT vmcnt drain: LDS ops complete, global loads stay in flight
#define BAR()  asm volatile("s_waitcnt lgkmcnt(0)\n\ts_barrier" ::: "memory")
#define SBAR() __builtin_amdgcn_sched_barrier(0)

__device__ __forceinline__ unsigned short f2bf(float f) {
    union { float f; uint32_t u; } v; v.f = f;
    uint32_t u = v.u;
    return (unsigned short)((u + 0x7FFFu + ((u >> 16) & 1u)) >> 16);
}
__device__ __forceinline__ float bf2f(unsigned short h) {
    union { uint32_t u; float f; } v; v.u = ((uint32_t)h) << 16; return v.f;
}
// packed f32->bf16 (RNE), 2 values -> 1 dword
__device__ __forceinline__ uint32_t cvtpk(float lo, float hi) {
    uint32_t d;
    asm("v_cvt_pk_bf16_f32 %0, %1, %2" : "=v"(d) : "v"(lo), "v"(hi));
    return d;
}
__device__ __forceinline__ float silu_mul(unsigned short h1u, unsigned short h3u) {
    float h1 = bf2f(h1u), h3 = bf2f(h3u);
    return h1 * h3 * __builtin_amdgcn_rcpf(1.f + __expf(-h1));
}

// ---------------- Router ----------------
__global__ __launch_bounds__(256) void k_router(
    const float* __restrict__ x, const float* __restrict__ gw,
    const float* __restrict__ bias,
    int* __restrict__ counts, int* __restrict__ tids, float* __restrict__ tws)
{
    __shared__ __align__(16) float xrow[Hdim];
    __shared__ float lg[Enum];
    const int t = blockIdx.x;
    const float* xr = x + (size_t)t * Hdim;

    for (int i = threadIdx.x; i < Hdim / 4; i += 256)
        ((f32x4*)xrow)[i] = ((const f32x4*)xr)[i];
    __syncthreads();

    const int lane = threadIdx.x & 63;
    const int wid  = threadIdx.x >> 6;
    for (int e = wid; e < Enum; e += 4) {
        const float* g = gw + (size_t)e * Hdim;
        float s = 0.f;
        for (int j = lane; j < Hdim; j += 64) s += xrow[j] * g[j];
        #pragma unroll
        for (int off = 32; off; off >>= 1) s += __shfl_xor(s, off);
        if (lane == 0) lg[e] = s;
    }
    __syncthreads();

    if (threadIdx.x == 0) {
        float m = lg[0];
        #pragma unroll
        for (int e = 1; e < Enum; ++e) m = fmaxf(m, lg[e]);
        float sc[Enum]; float sum = 0.f;
        #pragma unroll
        for (int e = 0; e < Enum; ++e) { float ex = expf(lg[e] - m); sc[e] = ex; sum += ex; }
        float inv = 1.f / sum;
        #pragma unroll
        for (int e = 0; e < Enum; ++e) sc[e] *= inv;
        int i0 = 0; float b0 = sc[0] + bias[0];
        #pragma unroll
        for (int e = 1; e < Enum; ++e) { float bb = sc[e] + bias[e]; if (bb > b0) { b0 = bb; i0 = e; } }
        int i1 = -1; float b1 = -1e30f;
        #pragma unroll
        for (int e = 0; e < Enum; ++e) {
            if (e == i0) continue;
            float bb = sc[e] + bias[e]; if (bb > b1) { b1 = bb; i1 = e; }
        }
        float w0 = sc[i0], w1v = sc[i1];
        float winv = 1.f / (w0 + w1v);
        w0 *= winv; w1v *= winv;
        int p0 = atomicAdd(&counts[i0], 1);
        tids[i0 * Ttok + p0] = t; tws[i0 * Ttok + p0] = w0;
        int p1 = atomicAdd(&counts[i1], 1);
        tids[i1 * Ttok + p1] = t; tws[i1 * Ttok + p1] = w1v;
    }
}

// ---------------- Gather: compact + bf16 + tile X ----------------
// Xg layout: [pc*256 + kg][row 0..63][8 halfs]; pad rows zeroed. grid (8, 48).
__global__ __launch_bounds__(256) void k_gather(
    const float* __restrict__ x, const int* __restrict__ counts,
    const int* __restrict__ tids, unsigned short* __restrict__ Xg)
{
    const int p = blockIdx.y;
    int pe = -1, c = 0, acc = 0;
    #pragma unroll
    for (int j = 0; j < Enum; ++j) {
        int nj = (counts[j] + 63) >> 6;
        if (pe < 0 && p < acc + nj) { pe = j; c = p - acc; }
        acc += nj;
    }
    if (pe < 0) return;
    const int Ne = counts[pe];
    const int s  = blockIdx.x;          // kg strip: kg in [s*32, s*32+32)
    const int r  = threadIdx.x & 63;
    const int kq = threadIdx.x >> 6;    // 0..3
    const int row = c * 64 + r;
    const bool valid = row < Ne;
    const int tok = valid ? tids[pe * Ttok + row] : 0;
    const float* xr = x + (size_t)tok * Hdim;

    #pragma unroll
    for (int j = 0; j < 8; ++j) {
        int kg = s * 32 + j * 4 + kq;
        uint4 o = make_uint4(0, 0, 0, 0);
        if (valid) {
            f32x4 p0 = *(const f32x4*)(xr + kg * 8);
            f32x4 p1 = *(const f32x4*)(xr + kg * 8 + 4);
            o.x = cvtpk(p0[0], p0[1]); o.y = cvtpk(p0[2], p0[3]);
            o.z = cvtpk(p1[0], p1[1]); o.w = cvtpk(p1[2], p1[3]);
        }
        *(uint4*)(Xg + ((size_t)(p * 256 + kg) * 64 + r) * 8) = o;
    }
}

// ---------------- Stage 2: H{1,3} = X @ W{1,3}, depth-4 pipelined ----------------
// grid (32 = mat2 x colblk16, 16 chunks, E), block 256. M=64, N=64, BK=64, NK=32.
union ShH {
    struct {
        unsigned short Xs[2][4096];       // 16 KB [buf][kg*512 + row*8 + j]
        unsigned short Ws[2][8][64][8];   // 16 KB [buf][kg][col][j]
    } a;
    unsigned short T[64][80];             // 10.2 KB epilogue bounce
};

__global__ __launch_bounds__(256, 2) void k_h(
    const unsigned short* __restrict__ Xg,
    const float* __restrict__ w1, const float* __restrict__ w3,
    const int* __restrict__ counts,
    unsigned short* __restrict__ H1, unsigned short* __restrict__ H3)
{
    const int e  = blockIdx.z;
    const int Ne = counts[e];
    const int c  = blockIdx.y;
    if (c * 64 >= Ne) return;
    int poff = 0;
    #pragma unroll
    for (int j = 0; j < Enum; ++j) if (j < e) poff += (counts[j] + 63) >> 6;
    const int pc   = poff + c;
    const int mat  = blockIdx.x >> 4;
    const int cb   = blockIdx.x & 15;
    const int col0 = cb * 64;
    const int tid  = threadIdx.x;
    const int lane = tid & 63;
    const int wid  = tid >> 6;
    const int l15  = lane & 15;
    const int kq   = lane >> 4;

    __shared__ ShH sh;

    const unsigned short* xsrc = Xg + (size_t)pc * 131072;
    const int wkg = tid >> 5;            // k-row group (8 rows each)
    const int wcp = (tid & 31) * 2;      // col pair
    const float* wsrc = (mat ? w3 : w1)
        + ((size_t)e * Hdim + wkg * 8) * Idim + col0 + wcp;
    unsigned short* Hm = mat ? H3 : H1;

    f32x4 acc[4];
    #pragma unroll
    for (int a = 0; a < 4; ++a) acc[a] = (f32x4)(0.f);

    const int NK = Hdim / 64; // 32 (mult of 4)

    auto xload = [&](int ks, short8& v0, short8& v1) {
        const unsigned short* p = xsrc + (size_t)ks * 4096;
        v0 = *(const short8*)(p + tid * 8);
        v1 = *(const short8*)(p + 2048 + tid * 8);
    };
    auto wload = [&](int ks, float2* wv) {
        const float* wp = wsrc + (size_t)ks * 64 * Idim;
        #pragma unroll
        for (int j = 0; j < 8; ++j) wv[j] = *(const float2*)(wp + (size_t)j * Idim);
    };
    auto stage = [&](int buf, short8 x0, short8 x1, const float2* wv) {
        *(short8*)&sh.a.Xs[buf][tid * 8]        = x0;
        *(short8*)&sh.a.Xs[buf][2048 + tid * 8] = x1;
        uint4 q0, q1;
        q0.x = cvtpk(wv[0].x, wv[1].x); q0.y = cvtpk(wv[2].x, wv[3].x);
        q0.z = cvtpk(wv[4].x, wv[5].x); q0.w = cvtpk(wv[6].x, wv[7].x);
        q1.x = cvtpk(wv[0].y, wv[1].y); q1.y = cvtpk(wv[2].y, wv[3].y);
        q1.z = cvtpk(wv[4].y, wv[5].y); q1.w = cvtpk(wv[6].y, wv[7].y);
        *(uint4*)&sh.a.Ws[buf][wkg][wcp][0]     = q0;
        *(uint4*)&sh.a.Ws[buf][wkg][wcp + 1][0] = q1;
    };
    auto mfma_step = [&](int buf) {
        #pragma unroll
        for (int ks2 = 0; ks2 < 2; ++ks2) {
            const int kgi = ks2 * 4 + kq;
            short8 b = *(const short8*)&sh.a.Ws[buf][kgi][wid * 16 + l15][0];
            #pragma unroll
            for (int fr = 0; fr < 4; ++fr) {
                short8 af = *(const short8*)&sh.a.Xs[buf][kgi * 512 + (fr * 16 + l15) * 8];
                acc[fr] = __builtin_amdgcn_mfma_f32_16x16x32_bf16(af, b, acc[fr], 0, 0, 0);
            }
        }
    };

    // depth-4 W sets, depth-2 X sets
    float2 wA[8], wB[8], wC[8], wD[8];
    short8 xA0, xA1, xB0, xB1;

    wload(0, wA); wload(1, wB); wload(2, wC); wload(3, wD);
    xload(0, xA0, xA1); xload(1, xB0, xB1);
    SBAR();
    stage(0, xA0, xA1, wA);
    BAR();

    for (int ks = 0; ks < NK; ks += 4) {
        // pos1: compute ks, stage ks+1
        if (ks + 4 < NK) wload(ks + 4, wA);
        xload(ks + 2, xA0, xA1);
        SBAR();
        mfma_step(0);
        stage(1, xB0, xB1, wB);
        SBAR();
        BAR();
        // pos2: compute ks+1, stage ks+2
        if (ks + 5 < NK) wload(ks + 5, wB);
        if (ks + 3 < NK) xload(ks + 3, xB0, xB1);
        SBAR();
        mfma_step(1);
        stage(0, xA0, xA1, wC);
        SBAR();
        BAR();
        // pos3: compute ks+2, stage ks+3
        if (ks + 6 < NK) wload(ks + 6, wC);
        if (ks + 4 < NK) xload(ks + 4, xA0, xA1);
        SBAR();
        mfma_step(0);
        stage(1, xB0, xB1, wD);
        SBAR();
        BAR();
        // pos4: compute ks+3, stage ks+4
        if (ks + 7 < NK) wload(ks + 7, wD);
        if (ks + 5 < NK) xload(ks + 5, xB0, xB1);
        SBAR();
        mfma_step(1);
        if (ks + 4 < NK) stage(0, xA0, xA1, wA);
        SBAR();
        BAR();
    }

    // epilogue: acc -> bf16 -> LDS bounce -> H tiled [pc*128 + KG][64][8]
    #pragma unroll
    for (int fr = 0; fr < 4; ++fr)
        #pragma unroll
        for (int k = 0; k < 4; ++k)
            sh.T[fr * 16 + kq * 4 + k][wid * 16 + l15] = f2bf(acc[fr][k]);
    __syncthreads();
    {
        const int r = tid & 63, kgw = tid >> 6;
        #pragma unroll
        for (int q = 0; q < 2; ++q) {
            int KGl = kgw * 2 + q;
            short8 v = *(const short8*)&sh.T[r][KGl * 8];
            *(short8*)(Hm + ((size_t)(pc * 128 + cb * 8 + KGl) * 64 + r) * 8) = v;
        }
    }
}

// ---------------- Stage 3: out += w * (silu(H1)*H3 @ W2), depth-4 pipelined ----------------
// grid (32, 16 chunks, E), block 256. M=64, N=64, BK=64, NK=16. Fuse in A-staging.
__global__ __launch_bounds__(256, 2) void k_o(
    const unsigned short* __restrict__ H1, const unsigned short* __restrict__ H3,
    const float* __restrict__ w2,
    const int* __restrict__ counts, const int* __restrict__ tids,
    const float* __restrict__ tws,
    float* __restrict__ out)
{
    const int e  = blockIdx.z;
    const int Ne = counts[e];
    const int c  = blockIdx.y;
    if (c * 64 >= Ne) return;
    int poff = 0;
    #pragma unroll
    for (int j = 0; j < Enum; ++j) if (j < e) poff += (counts[j] + 63) >> 6;
    const int pc   = poff + c;
    const int col0 = blockIdx.x * 64;
    const int tid  = threadIdx.x;
    const int lane = tid & 63;
    const int wid  = tid >> 6;
    const int l15  = lane & 15;
    const int kq   = lane >> 4;

    __shared__ __align__(16) unsigned short As[2][4096];      // 16 KB
    __shared__ __align__(16) unsigned short Ws[2][8][64][8];  // 16 KB

    const unsigned short* h1src = H1 + (size_t)pc * 65536;
    const unsigned short* h3src = H3 + (size_t)pc * 65536;
    const int wkg = tid >> 5;
    const int wcp = (tid & 31) * 2;
    const float* wsrc = w2 + ((size_t)e * Idim + wkg * 8) * Hdim + col0 + wcp;

    f32x4 acc[4];
    #pragma unroll
    for (int a = 0; a < 4; ++a) acc[a] = (f32x4)(0.f);

    const int NK = Idim / 64; // 16 (mult of 4)

    auto hload = [&](int ks, short8& a0, short8& a1, short8& b0, short8& b1) {
        a0 = *(const short8*)(h1src + (size_t)ks * 4096 + tid * 8);
        a1 = *(const short8*)(h1src + (size_t)ks * 4096 + 2048 + tid * 8);
        b0 = *(const short8*)(h3src + (size_t)ks * 4096 + tid * 8);
        b1 = *(const short8*)(h3src + (size_t)ks * 4096 + 2048 + tid * 8);
    };
    auto wload = [&](int ks, float2* wv) {
        const float* wp = wsrc + (size_t)ks * 64 * Hdim;
        #pragma unroll
        for (int j = 0; j < 8; ++j) wv[j] = *(const float2*)(wp + (size_t)j * Hdim);
    };
    auto stage = [&](int buf, short8 h10, short8 h11, short8 h30, short8 h31,
                     const float2* wv) {
        uint4 o0, o1;
        o0.x = cvtpk(silu_mul(h10[0], h30[0]), silu_mul(h10[1], h30[1]));
        o0.y = cvtpk(silu_mul(h10[2], h30[2]), silu_mul(h10[3], h30[3]));
        o0.z = cvtpk(silu_mul(h10[4], h30[4]), silu_mul(h10[5], h30[5]));
        o0.w = cvtpk(silu_mul(h10[6], h30[6]), silu_mul(h10[7], h30[7]));
        o1.x = cvtpk(silu_mul(h11[0], h31[0]), silu_mul(h11[1], h31[1]));
        o1.y = cvtpk(silu_mul(h11[2], h31[2]), silu_mul(h11[3], h31[3]));
        o1.z = cvtpk(silu_mul(h11[4], h31[4]), silu_mul(h11[5], h31[5]));
        o1.w = cvtpk(silu_mul(h11[6], h31[6]), silu_mul(h11[7], h31[7]));
        *(uint4*)&As[buf][tid * 8]        = o0;
        *(uint4*)&As[buf][2048 + tid * 8] = o1;
        uint4 q0, q1;
        q0.x = cvtpk(wv[0].x, wv[1].x); q0.y = cvtpk(wv[2].x, wv[3].x);
        q0.z = cvtpk(wv[4].x, wv[5].x); q0.w = cvtpk(wv[6].x, wv[7].x);
        q1.x = cvtpk(wv[0].y, wv[1].y); q1.y = cvtpk(wv[2].y, wv[3].y);
        q1.z = cvtpk(wv[4].y, wv[5].y); q1.w = cvtpk(wv[6].y, wv[7].y);
        *(uint4*)&Ws[buf][wkg][wcp][0]     = q0;
        *(uint4*)&Ws[buf][wkg][wcp + 1][0] = q1;
    };
    auto mfma_step = [&](int buf) {
        #pragma unroll
        for (int ks2 = 0; ks2 < 2; ++ks2) {
            const int kgi = ks2 * 4 + kq;
            short8 b = *(const short8*)&Ws[buf][kgi][wid * 16 + l15][0];
            #pragma unroll
            for (int fr = 0; fr < 4; ++fr) {
                short8 af = *(const short8*)&As[buf][kgi * 512 + (fr * 16 + l15) * 8];
                acc[fr] = __builtin_amdgcn_mfma_f32_16x16x32_bf16(af, b, acc[fr], 0, 0, 0);
            }
        }
    };

    float2 wA[8], wB[8], wC[8], wD[8];
    short8 h1A0, h1A1, h3A0, h3A1, h1B0, h1B1, h3B0, h3B1;

    wload(0, wA); wload(1, wB); wload(2, wC); wload(3, wD);
    hload(0, h1A0, h1A1, h3A0, h3A1);
    hload(1, h1B0, h1B1, h3B0, h3B1);
    SBAR();
    stage(0, h1A0, h1A1, h3A0, h3A1, wA);
    BAR();

    for (int ks = 0; ks < NK; ks += 4) {
        // pos1
        if (ks + 4 < NK) wload(ks + 4, wA);
        hload(ks + 2, h1A0, h1A1, h3A0, h3A1);
        SBAR();
        mfma_step(0);
        stage(1, h1B0, h1B1, h3B0, h3B1, wB);
        SBAR();
        BAR();
        // pos2
        if (ks + 5 < NK) wload(ks + 5, wB);
        if (ks + 3 < NK) hload(ks + 3, h1B0, h1B1, h3B0, h3B1);
        SBAR();
        mfma_step(1);
        stage(0, h1A0, h1A1, h3A0, h3A1, wC);
        SBAR();
        BAR();
        // pos3
        if (ks + 6 < NK) wload(ks + 6, wC);
        if (ks + 4 < NK) hload(ks + 4, h1A0, h1A1, h3A0, h3A1);
        SBAR();
        mfma_step(0);
        stage(1, h1B0, h1B1, h3B0, h3B1, wD);
        SBAR();
        BAR();
        // pos4
        if (ks + 7 < NK) wload(ks + 7, wD);
        if (ks + 5 < NK) hload(ks + 5, h1B0, h1B1, h3B0, h3B1);
        SBAR();
        mfma_step(1);
        if (ks + 4 < NK) stage(0, h1A0, h1A1, h3A0, h3A1, wA);
        SBAR();
        BAR();
    }

    #pragma unroll
    for (int fr = 0; fr < 4; ++fr) {
        #pragma unroll
        for (int k = 0; k < 4; ++k) {
            int grow = c * 64 + fr * 16 + kq * 4 + k;
            if (grow < Ne) {
                int   tk = tids[e * Ttok + grow];
                float w  = tws[e * Ttok + grow];
                atomicAdd(&out[(size_t)tk * Hdim + col0 + wid * 16 + l15], w * acc[fr][k]);
            }
        }
    }
}

extern "C" void kernel_launch(void* const* d_in, const int* in_sizes, int n_in,
                              void* d_out, int out_size, void* d_ws, size_t ws_size,
                              hipStream_t stream)
{
    const float* x    = (const float*)d_in[0];
    const float* gw   = (const float*)d_in[1];
    const float* bias = (const float*)d_in[2];
    const float* w1   = (const float*)d_in[3];
    const float* w3   = (const float*)d_in[4];
    const float* w2   = (const float*)d_in[5];
    float* out = (float*)d_out;

    char* ws = (char*)d_ws;
    int*            counts = (int*)ws;                         // @0        64 B
    int*            tids   = (int*)(ws + 1024);                // @1K       64 KB
    float*          tws    = (float*)(ws + 66560);             // @65K      64 KB
    unsigned short* Xg     = (unsigned short*)(ws + 132096);   // 12.58 MB (48 chunks)
    unsigned short* H1     = (unsigned short*)(ws + 12715008); // 6.29 MB
    unsigned short* H3     = (unsigned short*)(ws + 19006464); // 6.29 MB -> end ~25.3 MB

    hipMemsetAsync(counts, 0, Enum * sizeof(int), stream);
    hipMemsetAsync(out, 0, (size_t)Ttok * Hdim * sizeof(float), stream);

    k_router<<<dim3(Ttok), dim3(256), 0, stream>>>(x, gw, bias, counts, tids, tws);
    k_gather<<<dim3(8, 48), dim3(256), 0, stream>>>(x, counts, tids, Xg);
    k_h<<<dim3(32, 16, Enum), dim3(256), 0, stream>>>(Xg, w1, w3, counts, H1, H3);
    k_o<<<dim3(32, 16, Enum), dim3(256), 0, stream>>>(H1, H3, w2, counts, tids, tws, out);
}